// Round 5
// baseline (150.455 us; speedup 1.0000x reference)
//
#include <hip/hip_runtime.h>

namespace {
constexpr int HH = 56, WW = 56;
constexpr int CPLANE = HH * WW;          // 3136 floats per (b,ch) plane
constexpr int LSTRIDE = 516;             // LDS h-plane stride (8*64 + 4 pad) -> 4 mod 32 banks

// ---------------- Kernel A: channel mix ----------------
// t4 layout: [b][h][m][i][56] floats (12.85 MB in d_ws)
__global__ __launch_bounds__(128, 2) void chanmix_kernel(
    const float* __restrict__ x,
    const float* __restrict__ w1,
    float* __restrict__ t4g)
{
    __shared__ float4 w1s[64];
    const int tid = threadIdx.x;
    if (tid < 64) w1s[tid] = ((const float4*)w1)[tid];
    __syncthreads();

    const int b  = blockIdx.x >> 3;
    const int hg = blockIdx.x & 7;       // 8 groups of 7 h-rows
    const int h0 = hg * 7;

    if (tid >= 98) return;               // 7 rows x 14 w-quads
    const int rh = tid / 14;
    const int wq = tid - rh * 14;
    const int h  = h0 + rh;

    const float* xp = x + ((size_t)b * 128 * HH + h) * WW + wq * 4;

    float acc[2][4][4];                  // [m][i][q]
    #pragma unroll
    for (int m = 0; m < 2; ++m)
        #pragma unroll
        for (int i = 0; i < 4; ++i)
            #pragma unroll
            for (int q = 0; q < 4; ++q) acc[m][i][q] = 0.f;

    #pragma unroll 2
    for (int ch0 = 0; ch0 < 128; ch0 += 8) {
        float4 xv[8];
        #pragma unroll
        for (int k = 0; k < 8; ++k)
            xv[k] = *(const float4*)(xp + (size_t)(ch0 + k) * CPLANE);
        #pragma unroll
        for (int k = 0; k < 8; ++k) {
            const int m = k & 1;                  // ch0 even -> m = k&1 (compile-time)
            const float4 wv = w1s[(ch0 + k) >> 1];
            const float xk[4] = {xv[k].x, xv[k].y, xv[k].z, xv[k].w};
            const float wk[4] = {wv.x, wv.y, wv.z, wv.w};
            #pragma unroll
            for (int i = 0; i < 4; ++i)
                #pragma unroll
                for (int q = 0; q < 4; ++q)
                    acc[m][i][q] = fmaf(xk[q], wk[i], acc[m][i][q]);
        }
    }

    float* tp = t4g + (size_t)(b * HH + h) * 448 + wq * 4;   // 448 = 2*4*56
    #pragma unroll
    for (int m = 0; m < 2; ++m)
        #pragma unroll
        for (int i = 0; i < 4; ++i)
            *(float4*)(tp + (m * 4 + i) * WW) =
                make_float4(acc[m][i][0], acc[m][i][1], acc[m][i][2], acc[m][i][3]);
}

// ---------------- Kernel B: 9-tap conv along w + roll(+1,H) ----------------
__global__ __launch_bounds__(256, 2) void conv_kernel(
    const float* __restrict__ t4g,
    const float* __restrict__ w0,
    float* __restrict__ out)
{
    __shared__ float ls[14 * LSTRIDE];   // [h][m*4+i][64]: idx 0,1 pad, 2..57 data(w+2), 58,59 pad
    __shared__ float w0s[576];

    const int tid = threadIdx.x;
    const int cg  = blockIdx.x & 3;              // 32-channel group
    const int hg  = (blockIdx.x >> 2) & 3;       // 14 h-rows
    const int b   = blockIdx.x >> 4;
    const int h0  = hg * 14;

    for (int t = tid; t < 576; t += 256) w0s[t] = w0[t];

    // zero pad slots (disjoint from data writes)
    if (tid < 224) {
        const int row  = tid >> 1;               // h*8 + mi
        const int half = tid & 1;
        const int hh = row >> 3, mi = row & 7;
        *(float2*)&ls[hh * LSTRIDE + mi * 64 + (half ? 58 : 0)] = make_float2(0.f, 0.f);
    }

    // load this block's t4 chunk: 14*2*4*56 floats = 1568 float4, contiguous
    const float4* src = (const float4*)(t4g + (size_t)(b * HH + h0) * 448);
    #pragma unroll
    for (int k = 0; k < 7; ++k) {
        const int idx = k * 256 + tid;
        if (idx < 1568) {
            const float4 v = src[idx];
            const int row = idx / 14, wq = idx - row * 14;
            const int hh = row >> 3, mi = row & 7;
            float* d = &ls[hh * LSTRIDE + mi * 64 + 2 + 4 * wq];
            *(float2*)d       = make_float2(v.x, v.y);
            *(float2*)(d + 2) = make_float2(v.z, v.w);
        }
    }
    __syncthreads();

    if (tid >= 196) return;                      // 14 rows x 14 w-quads
    const int rh = tid / 14;
    const int wq = tid - rh * 14;
    const int l0 = 4 * wq;

    // window registers: v[m][i][k] = t4[h][m][i][w = l0-2+k], zero-padded
    float v[2][4][8];
    #pragma unroll
    for (int m = 0; m < 2; ++m)
        #pragma unroll
        for (int i = 0; i < 4; ++i) {
            const float* p = &ls[rh * LSTRIDE + (m * 4 + i) * 64 + l0];
            const float4 p0 = *(const float4*)p;
            const float4 p1 = *(const float4*)(p + 4);
            v[m][i][0] = p0.x; v[m][i][1] = p0.y; v[m][i][2] = p0.z; v[m][i][3] = p0.w;
            v[m][i][4] = p1.x; v[m][i][5] = p1.y; v[m][i][6] = p1.z; v[m][i][7] = p1.w;
        }

    const int h_out = (h0 + rh + 1) % HH;
    float* obase = out + ((size_t)b * 128 * HH + h_out) * WW + l0;

    #pragma unroll 2
    for (int jj = 0; jj < 8; ++jj) {
        const int j = cg * 8 + jj;
        // collapse 18 taps -> per-m 5 effective taps (w0 independent of i)
        float W[2][5], fix0[2], fix3[2];
        #pragma unroll
        for (int m = 0; m < 2; ++m) {
            const float w00 = w0s[((m * 3 + 0) * 3 + 0) * 32 + j];
            const float w01 = w0s[((m * 3 + 0) * 3 + 1) * 32 + j];
            const float w02 = w0s[((m * 3 + 0) * 3 + 2) * 32 + j];
            const float w10 = w0s[((m * 3 + 1) * 3 + 0) * 32 + j];
            const float w11 = w0s[((m * 3 + 1) * 3 + 1) * 32 + j];
            const float w12 = w0s[((m * 3 + 1) * 3 + 2) * 32 + j];
            const float w20 = w0s[((m * 3 + 2) * 3 + 0) * 32 + j];
            const float w21 = w0s[((m * 3 + 2) * 3 + 1) * 32 + j];
            const float w22 = w0s[((m * 3 + 2) * 3 + 2) * 32 + j];
            W[m][0] = w00;
            W[m][1] = w01 + w10;
            W[m][2] = w02 + w11 + w20;
            W[m][3] = w12 + w21;
            W[m][4] = w22;
            fix0[m] = w02;   // kB=0 invalid at w=0  (only kA=2 term nonzero)
            fix3[m] = w20;   // kB=2 invalid at w=55 (only kA=0 term nonzero)
        }
        #pragma unroll
        for (int i = 0; i < 4; ++i) {
            float o0 = 0.f, o1 = 0.f, o2 = 0.f, o3 = 0.f;
            #pragma unroll
            for (int m = 0; m < 2; ++m)
                #pragma unroll
                for (int d = 0; d < 5; ++d) {
                    const float wd = W[m][d];
                    o0 = fmaf(v[m][i][d],     wd, o0);
                    o1 = fmaf(v[m][i][d + 1], wd, o1);
                    o2 = fmaf(v[m][i][d + 2], wd, o2);
                    o3 = fmaf(v[m][i][d + 3], wd, o3);
                }
            if (wq == 0)  o0 -= v[0][i][2] * fix0[0] + v[1][i][2] * fix0[1];  // w=0
            if (wq == 13) o3 -= v[0][i][5] * fix3[0] + v[1][i][5] * fix3[1];  // w=55
            const int c = j * 4 + i;
            *(float4*)(obase + (size_t)c * CPLANE) = make_float4(o0, o1, o2, o3);
        }
    }
}
} // namespace

extern "C" void kernel_launch(void* const* d_in, const int* in_sizes, int n_in,
                              void* d_out, int out_size, void* d_ws, size_t ws_size,
                              hipStream_t stream) {
    const float* x  = (const float*)d_in[0];
    const float* w0 = (const float*)d_in[1];
    const float* w1 = (const float*)d_in[2];
    float* out = (float*)d_out;
    float* t4g = (float*)d_ws;           // 128*56*2*4*56 floats = 12.85 MB

    chanmix_kernel<<<dim3(128 * 8), dim3(128), 0, stream>>>(x, w1, t4g);
    conv_kernel<<<dim3(128 * 16), dim3(256), 0, stream>>>(t4g, w0, out);
}

// Round 6
// 142.111 us; speedup vs baseline: 1.0587x; 1.0587x over previous
//
#include <hip/hip_runtime.h>

namespace {
constexpr int HH = 56, WW = 56;
constexpr int CPLANE = HH * WW;          // 3136 floats per (b,ch) plane

// ---------------- Kernel A: channel mix ----------------
// t4 layout: [b][h][m*4+i][56] floats (12.85 MB in d_ws)
// grid = (b, h-half): 256 blocks; block = 448 (392 compute threads).
__global__ __launch_bounds__(448, 1) void chanmix_kernel(
    const float* __restrict__ x,
    const float* __restrict__ w1,
    float* __restrict__ t4g)
{
    __shared__ float4 w1s[64];
    const int tid = threadIdx.x;
    if (tid < 64) w1s[tid] = ((const float4*)w1)[tid];
    __syncthreads();

    const int b  = blockIdx.x >> 1;
    const int h0 = (blockIdx.x & 1) * 28;
    if (tid >= 392) return;              // 28 rows x 14 w-quads

    const int rh = tid / 14;
    const int w0 = (tid - rh * 14) * 4;
    const float* xp = x + ((size_t)b * 128 * HH + (h0 + rh)) * WW + w0;

    float acc[2][4][4] = {};             // [m][i][q]

    for (int c0 = 0; c0 < 128; c0 += 8) {
        float4 xv[8];
        #pragma unroll
        for (int k = 0; k < 8; ++k)
            xv[k] = *(const float4*)(xp + (size_t)(c0 + k) * CPLANE);
        #pragma unroll
        for (int k = 0; k < 8; ++k) {
            const int m = k & 1;                 // c0 even -> compile-time
            const float4 wv = w1s[(c0 + k) >> 1];
            const float xk[4] = {xv[k].x, xv[k].y, xv[k].z, xv[k].w};
            const float wk[4] = {wv.x, wv.y, wv.z, wv.w};
            #pragma unroll
            for (int i = 0; i < 4; ++i)
                #pragma unroll
                for (int q = 0; q < 4; ++q)
                    acc[m][i][q] = fmaf(xk[q], wk[i], acc[m][i][q]);
        }
    }

    float* tp = t4g + (size_t)(b * HH + h0 + rh) * 448 + w0;   // 448 = 8*56
    #pragma unroll
    for (int m = 0; m < 2; ++m)
        #pragma unroll
        for (int i = 0; i < 4; ++i)
            *(float4*)(tp + (m * 4 + i) * WW) =
                make_float4(acc[m][i][0], acc[m][i][1], acc[m][i][2], acc[m][i][3]);
}

// ---------------- Kernel B: collapsed 2x5-tap conv + roll(+1,H) ----------------
// grid = (b, h-quarter): 512 blocks; block = 256 (196 compute threads).
// Each block: stage 14-row t4 slab (25 KB contiguous) once, emit ALL 128
// output channels; writes walk consecutive channel planes (1 KB/wave-store).
__global__ __launch_bounds__(256, 2) void conv_kernel(
    const float* __restrict__ t4g,
    const float* __restrict__ w0,
    float* __restrict__ out)
{
    __shared__ float ls[14][8][60];      // [h][m*4+i][pad2 | w=0..55 | pad2]
    __shared__ float Wc[32][2][5];       // collapsed taps
    __shared__ float fx0[32][2], fx3[32][2];

    const int tid = threadIdx.x;
    const int b   = blockIdx.x >> 2;
    const int h0  = (blockIdx.x & 3) * 14;

    // collapsed weights (w0 is independent of i)
    if (tid < 64) {
        const int j = tid >> 1, m = tid & 1;
        float w[3][3];
        #pragma unroll
        for (int kB = 0; kB < 3; ++kB)
            #pragma unroll
            for (int kA = 0; kA < 3; ++kA)
                w[kB][kA] = w0[((m * 3 + kB) * 3 + kA) * 32 + j];
        Wc[j][m][0] = w[0][0];
        Wc[j][m][1] = w[0][1] + w[1][0];
        Wc[j][m][2] = w[0][2] + w[1][1] + w[2][0];
        Wc[j][m][3] = w[1][2] + w[2][1];
        Wc[j][m][4] = w[2][2];
        fx0[j][m] = w[0][2];             // kB=0 invalid at w=0
        fx3[j][m] = w[2][0];             // kB=2 invalid at w=55
    }

    // zero pad slots (disjoint from data writes)
    if (tid < 224) {
        const int row  = tid >> 1;       // h*8 + mi
        const int half = tid & 1;
        *(float2*)&ls[row >> 3][row & 7][half ? 58 : 0] = make_float2(0.f, 0.f);
    }

    // stage t4 slab: 14*8*56 floats = 1568 float4, fully contiguous in global
    const float4* src = (const float4*)(t4g + (size_t)(b * HH + h0) * 448);
    #pragma unroll
    for (int k = 0; k < 7; ++k) {
        const int idx = k * 256 + tid;
        if (idx < 1568) {
            const float4 v = src[idx];
            const int row = idx / 14, wq = idx - row * 14;
            float* d = &ls[row >> 3][row & 7][2 + 4 * wq];
            *(float2*)d       = make_float2(v.x, v.y);
            *(float2*)(d + 2) = make_float2(v.z, v.w);
        }
    }
    __syncthreads();

    if (tid >= 196) return;              // 14 rows x 14 w-quads
    const int rh = tid / 14;
    const int wq = tid - rh * 14;
    const int l0 = 4 * wq;

    // window registers: v[m][i][k] = t4[h][m][i][w = l0-2+k] (zero-padded)
    float v[2][4][8];
    #pragma unroll
    for (int m = 0; m < 2; ++m)
        #pragma unroll
        for (int i = 0; i < 4; ++i) {
            const float* p = &ls[rh][m * 4 + i][l0];   // 16B-aligned
            const float4 p0 = *(const float4*)p;
            const float4 p1 = *(const float4*)(p + 4);
            v[m][i][0] = p0.x; v[m][i][1] = p0.y; v[m][i][2] = p0.z; v[m][i][3] = p0.w;
            v[m][i][4] = p1.x; v[m][i][5] = p1.y; v[m][i][6] = p1.z; v[m][i][7] = p1.w;
        }

    const int h_out = (h0 + rh + 1) % HH;
    float* obase = out + ((size_t)b * 128 * HH + h_out) * WW + l0;

    #pragma unroll 2
    for (int j = 0; j < 32; ++j) {
        float W[2][5], f0[2], f3[2];
        #pragma unroll
        for (int m = 0; m < 2; ++m) {
            #pragma unroll
            for (int d = 0; d < 5; ++d) W[m][d] = Wc[j][m][d];
            f0[m] = fx0[j][m];
            f3[m] = fx3[j][m];
        }
        #pragma unroll
        for (int i = 0; i < 4; ++i) {
            float o0 = 0.f, o1 = 0.f, o2 = 0.f, o3 = 0.f;
            #pragma unroll
            for (int m = 0; m < 2; ++m)
                #pragma unroll
                for (int d = 0; d < 5; ++d) {
                    const float wd = W[m][d];
                    o0 = fmaf(v[m][i][d],     wd, o0);
                    o1 = fmaf(v[m][i][d + 1], wd, o1);
                    o2 = fmaf(v[m][i][d + 2], wd, o2);
                    o3 = fmaf(v[m][i][d + 3], wd, o3);
                }
            if (wq == 0)  o0 -= v[0][i][2] * f0[0] + v[1][i][2] * f0[1];  // w=0
            if (wq == 13) o3 -= v[0][i][5] * f3[0] + v[1][i][5] * f3[1];  // w=55
            *(float4*)(obase + (size_t)(j * 4 + i) * CPLANE) = make_float4(o0, o1, o2, o3);
        }
    }
}
} // namespace

extern "C" void kernel_launch(void* const* d_in, const int* in_sizes, int n_in,
                              void* d_out, int out_size, void* d_ws, size_t ws_size,
                              hipStream_t stream) {
    const float* x  = (const float*)d_in[0];
    const float* w0 = (const float*)d_in[1];
    const float* w1 = (const float*)d_in[2];
    float* out = (float*)d_out;
    float* t4g = (float*)d_ws;           // 128*56*8*56 floats = 12.85 MB

    chanmix_kernel<<<dim3(128 * 2), dim3(448), 0, stream>>>(x, w1, t4g);
    conv_kernel<<<dim3(128 * 4), dim3(256), 0, stream>>>(t4g, w0, out);
}

// Round 8
// 131.037 us; speedup vs baseline: 1.1482x; 1.0845x over previous
//
#include <hip/hip_runtime.h>

namespace {
constexpr int HH = 56, WW = 56;
constexpr int CPLANE = HH * WW;          // 3136 floats per (b,ch) plane

// One fused pass: block = (b, 14-row h-group), 512 blocks x 256 threads.
// Stage 1: channel-mix x[b,:,rows,:] -> t4 in LDS (1KB-contiguous wave loads,
//          software-pipelined). Stage 2: collapsed 2x5-tap conv along w,
//          roll(+1,H), 1KB-contiguous wave stores over consecutive planes.
__global__ __launch_bounds__(256, 2) void fused_kernel(
    const float* __restrict__ x,
    const float* __restrict__ w0,
    const float* __restrict__ w1,
    float* __restrict__ out)
{
    __shared__ float  ls[14][9][60];     // [rh][mi(+pad)][pad2|w 0..55|pad2]; stride 540 breaks bank alias
    __shared__ float  Wc[32][2][5];      // collapsed taps
    __shared__ float  fx0[32][2], fx3[32][2];
    __shared__ float4 w1s[64];

    const int tid = threadIdx.x;
    const int b   = blockIdx.x >> 2;
    const int h0  = (blockIdx.x & 3) * 14;

    if (tid < 64) w1s[tid] = ((const float4*)w1)[tid];

    if (tid >= 64 && tid < 128) {        // collapsed weights (w0 independent of i)
        const int j = (tid - 64) >> 1, m = (tid - 64) & 1;
        float w[3][3];
        #pragma unroll
        for (int kB = 0; kB < 3; ++kB)
            #pragma unroll
            for (int kA = 0; kA < 3; ++kA)
                w[kB][kA] = w0[((m * 3 + kB) * 3 + kA) * 32 + j];
        Wc[j][m][0] = w[0][0];
        Wc[j][m][1] = w[0][1] + w[1][0];
        Wc[j][m][2] = w[0][2] + w[1][1] + w[2][0];
        Wc[j][m][3] = w[1][2] + w[2][1];
        Wc[j][m][4] = w[2][2];
        fx0[j][m] = w[0][2];             // kB=0 invalid at w=0
        fx3[j][m] = w[2][0];             // kB=2 invalid at w=55
    }

    // zero pad slots (disjoint from stage-1 data writes, which cover idx 2..57)
    if (tid < 224) {
        const int row  = tid >> 1;       // rh*8 + mi
        const int half = tid & 1;
        *(float2*)&ls[row >> 3][row & 7][half ? 58 : 0] = make_float2(0.f, 0.f);
    }

    __syncthreads();                     // w1s/Wc/pads visible to all waves

    const int  rh = tid / 14;
    const int  wq = tid - rh * 14;
    const int  l0 = 4 * wq;
    const bool active = (tid < 196);     // 14 rows x 14 w-quads

    // ---- stage 1: channel mix into LDS ----
    if (active) {
        const float* xp = x + ((size_t)b * 128 * HH + (h0 + rh)) * WW + l0;
        float acc[2][4][4] = {};         // [m][i][q]
        float4 pA[8], pB[8];

        auto LOADG = [&](float4* buf, int c0) {
            #pragma unroll
            for (int k = 0; k < 8; ++k)
                buf[k] = *(const float4*)(xp + (size_t)(c0 + k) * CPLANE);
        };
        auto FMA8 = [&](const float4* buf, int c0) {
            #pragma unroll
            for (int k = 0; k < 8; ++k) {
                const int m = k & 1;     // c0 even -> compile-time parity
                const float4 wv = w1s[(c0 + k) >> 1];
                const float xk[4] = {buf[k].x, buf[k].y, buf[k].z, buf[k].w};
                const float wk[4] = {wv.x, wv.y, wv.z, wv.w};
                #pragma unroll
                for (int i = 0; i < 4; ++i)
                    #pragma unroll
                    for (int q = 0; q < 4; ++q)
                        acc[m][i][q] = fmaf(xk[q], wk[i], acc[m][i][q]);
            }
        };

        LOADG(pA, 0);
        #pragma unroll
        for (int c0 = 0; c0 < 112; c0 += 16) {
            LOADG(pB, c0 + 8);
            FMA8(pA, c0);
            LOADG(pA, c0 + 16);
            FMA8(pB, c0 + 8);
        }
        LOADG(pB, 120);
        FMA8(pA, 112);
        FMA8(pB, 120);

        #pragma unroll
        for (int m = 0; m < 2; ++m)
            #pragma unroll
            for (int i = 0; i < 4; ++i) {
                *(float2*)&ls[rh][m * 4 + i][2 + l0]     = make_float2(acc[m][i][0], acc[m][i][1]);
                *(float2*)&ls[rh][m * 4 + i][2 + l0 + 2] = make_float2(acc[m][i][2], acc[m][i][3]);
            }
    }
    __syncthreads();

    // ---- stage 2: collapsed conv + roll ----
    if (!active) return;

    float v[2][4][8];                    // window t4[h][m][i][w = l0-2+k]
    #pragma unroll
    for (int m = 0; m < 2; ++m)
        #pragma unroll
        for (int i = 0; i < 4; ++i) {
            const float* p = &ls[rh][m * 4 + i][l0];   // 16B-aligned
            const float4 p0 = *(const float4*)p;
            const float4 p1 = *(const float4*)(p + 4);
            v[m][i][0] = p0.x; v[m][i][1] = p0.y; v[m][i][2] = p0.z; v[m][i][3] = p0.w;
            v[m][i][4] = p1.x; v[m][i][5] = p1.y; v[m][i][6] = p1.z; v[m][i][7] = p1.w;
        }

    const int h_out = (h0 + rh + 1) % HH;
    float* obase = out + ((size_t)b * 128 * HH + h_out) * WW + l0;

    #pragma unroll 2
    for (int j = 0; j < 32; ++j) {
        float W[2][5], f0[2], f3[2];
        #pragma unroll
        for (int m = 0; m < 2; ++m) {
            #pragma unroll
            for (int d = 0; d < 5; ++d) W[m][d] = Wc[j][m][d];
            f0[m] = fx0[j][m];
            f3[m] = fx3[j][m];
        }
        #pragma unroll
        for (int i = 0; i < 4; ++i) {
            float o0 = 0.f, o1 = 0.f, o2 = 0.f, o3 = 0.f;
            #pragma unroll
            for (int m = 0; m < 2; ++m)
                #pragma unroll
                for (int d = 0; d < 5; ++d) {
                    const float wd = W[m][d];
                    o0 = fmaf(v[m][i][d],     wd, o0);
                    o1 = fmaf(v[m][i][d + 1], wd, o1);
                    o2 = fmaf(v[m][i][d + 2], wd, o2);
                    o3 = fmaf(v[m][i][d + 3], wd, o3);
                }
            if (wq == 0)  o0 -= v[0][i][2] * f0[0] + v[1][i][2] * f0[1];  // w=0
            if (wq == 13) o3 -= v[0][i][5] * f3[0] + v[1][i][5] * f3[1];  // w=55
            *(float4*)(obase + (size_t)(j * 4 + i) * CPLANE) = make_float4(o0, o1, o2, o3);
        }
    }
}
} // namespace

extern "C" void kernel_launch(void* const* d_in, const int* in_sizes, int n_in,
                              void* d_out, int out_size, void* d_ws, size_t ws_size,
                              hipStream_t stream) {
    const float* x  = (const float*)d_in[0];
    const float* w0 = (const float*)d_in[1];
    const float* w1 = (const float*)d_in[2];
    float* out = (float*)d_out;
    fused_kernel<<<dim3(128 * 4), dim3(256), 0, stream>>>(x, w0, w1, out);
}

// Round 9
// 127.116 us; speedup vs baseline: 1.1836x; 1.0308x over previous
//
#include <hip/hip_runtime.h>

namespace {
constexpr int HH = 56, WW = 56;
constexpr int CPLANE = HH * WW;          // 3136 floats per (b,ch) plane

// Block = one (b,h) row, 128 threads; grid = 7168 -> ~16 resident blocks/CU.
// Stage 1: j split across lane-quads (js owns 16 j's), float4 x loads in two
//          8-deep batches, quad shfl-reduce, lane js writes the i=js row.
// Stage 2: collapsed 2x5-tap conv along w + roll(+1,H); 14 items/thread.
__global__ __launch_bounds__(128, 4) void fused_kernel(
    const float* __restrict__ x,
    const float* __restrict__ w0,
    const float* __restrict__ w1,
    float* __restrict__ out)
{
    __shared__ float  t4s[2][4][60];     // [m][i][pad2|w 0..55|pad2]
    __shared__ float  Wc[32][2][5];      // collapsed taps
    __shared__ float  fx0[32][2], fx3[32][2];
    __shared__ float4 w1s[64];

    const int tid = threadIdx.x;
    const int b   = blockIdx.x / HH;
    const int h   = blockIdx.x - b * HH;

    if (tid < 64) {
        w1s[tid] = ((const float4*)w1)[tid];
    } else {                             // tid 64..127: collapsed weights
        const int j = (tid - 64) >> 1, m = (tid - 64) & 1;
        float w[3][3];
        #pragma unroll
        for (int kB = 0; kB < 3; ++kB)
            #pragma unroll
            for (int kA = 0; kA < 3; ++kA)
                w[kB][kA] = w0[((m * 3 + kB) * 3 + kA) * 32 + j];
        Wc[j][m][0] = w[0][0];
        Wc[j][m][1] = w[0][1] + w[1][0];
        Wc[j][m][2] = w[0][2] + w[1][1] + w[2][0];
        Wc[j][m][3] = w[1][2] + w[2][1];
        Wc[j][m][4] = w[2][2];
        fx0[j][m] = w[0][2];             // kB=0 invalid at w=0
        fx3[j][m] = w[2][0];             // kB=2 invalid at w=55
    }
    if (tid < 16) {                      // zero pad slots (idx 0,1,58,59)
        const int row = tid >> 1, half = tid & 1;   // row = m*4+i
        *(float2*)&t4s[row >> 2][row & 3][half ? 58 : 0] = make_float2(0.f, 0.f);
    }
    __syncthreads();                     // weights/pads visible to all waves

    // ---- stage 1: channel mix, j quad-split ----
    if (tid < 112) {
        const int js = tid & 3;          // owns j = js*16 .. js*16+15
        const int m  = (tid >> 2) & 1;
        const int lq = tid >> 3;         // 0..13
        const int l0 = lq * 4;
        const float*  xp = x + ((size_t)(b * 128 + 2 * (js * 16) + m) * HH + h) * WW + l0;
        const size_t  jstride = (size_t)2 * CPLANE;    // j -> j+1 = 2 channels

        float acc[4][4] = {};            // [i][q]
        float4 pA[8], pB[8];

        auto LOADG = [&](float4* buf, int j0) {
            #pragma unroll
            for (int k = 0; k < 8; ++k)
                buf[k] = *(const float4*)(xp + (size_t)(j0 + k) * jstride);
        };
        auto FMA8 = [&](const float4* buf, int j0) {
            #pragma unroll
            for (int k = 0; k < 8; ++k) {
                const float4 wv = w1s[js * 16 + j0 + k];
                const float xk[4] = {buf[k].x, buf[k].y, buf[k].z, buf[k].w};
                const float wk[4] = {wv.x, wv.y, wv.z, wv.w};
                #pragma unroll
                for (int i = 0; i < 4; ++i)
                    #pragma unroll
                    for (int q = 0; q < 4; ++q)
                        acc[i][q] = fmaf(xk[q], wk[i], acc[i][q]);
            }
        };

        LOADG(pA, 0);
        LOADG(pB, 8);
        FMA8(pA, 0);
        FMA8(pB, 8);

        // quad allreduce over js (lane bits 0-1)
        #pragma unroll
        for (int i = 0; i < 4; ++i)
            #pragma unroll
            for (int q = 0; q < 4; ++q) {
                acc[i][q] += __shfl_xor(acc[i][q], 1);
                acc[i][q] += __shfl_xor(acc[i][q], 2);
            }

        // lane js keeps row i=js (static selects; no dynamic reg indexing)
        const float o0 = js == 0 ? acc[0][0] : js == 1 ? acc[1][0] : js == 2 ? acc[2][0] : acc[3][0];
        const float o1 = js == 0 ? acc[0][1] : js == 1 ? acc[1][1] : js == 2 ? acc[2][1] : acc[3][1];
        const float o2 = js == 0 ? acc[0][2] : js == 1 ? acc[1][2] : js == 2 ? acc[2][2] : acc[3][2];
        const float o3 = js == 0 ? acc[0][3] : js == 1 ? acc[1][3] : js == 2 ? acc[2][3] : acc[3][3];

        *(float2*)&t4s[m][js][2 + l0]     = make_float2(o0, o1);
        *(float2*)&t4s[m][js][2 + l0 + 2] = make_float2(o2, o3);
    }
    __syncthreads();

    // ---- stage 2: collapsed conv + roll; 1792 items over 128 threads ----
    const int h_out = (h + 1) % HH;
    float* ob = out + ((size_t)b * 128 * HH + h_out) * WW;

    #pragma unroll 2
    for (int it = 0; it < 14; ++it) {
        const int item = it * 128 + tid;
        const int c  = item / 14;
        const int wq = item - c * 14;
        const int l0 = wq * 4;
        const int j  = c >> 2;
        const int i  = c & 3;

        const float* p0 = &t4s[0][i][l0];
        const float* p1 = &t4s[1][i][l0];
        const float4 a0 = *(const float4*)p0, b0 = *(const float4*)(p0 + 4);
        const float4 a1 = *(const float4*)p1, b1 = *(const float4*)(p1 + 4);
        const float v0[8] = {a0.x, a0.y, a0.z, a0.w, b0.x, b0.y, b0.z, b0.w};
        const float v1[8] = {a1.x, a1.y, a1.z, a1.w, b1.x, b1.y, b1.z, b1.w};

        float o0 = 0.f, o1 = 0.f, o2 = 0.f, o3 = 0.f;
        #pragma unroll
        for (int d = 0; d < 5; ++d) {
            const float wd0 = Wc[j][0][d];
            o0 = fmaf(v0[d],     wd0, o0);
            o1 = fmaf(v0[d + 1], wd0, o1);
            o2 = fmaf(v0[d + 2], wd0, o2);
            o3 = fmaf(v0[d + 3], wd0, o3);
        }
        #pragma unroll
        for (int d = 0; d < 5; ++d) {
            const float wd1 = Wc[j][1][d];
            o0 = fmaf(v1[d],     wd1, o0);
            o1 = fmaf(v1[d + 1], wd1, o1);
            o2 = fmaf(v1[d + 2], wd1, o2);
            o3 = fmaf(v1[d + 3], wd1, o3);
        }

        if (wq == 0)  o0 -= v0[2] * fx0[j][0] + v1[2] * fx0[j][1];   // w=0
        if (wq == 13) o3 -= v0[5] * fx3[j][0] + v1[5] * fx3[j][1];   // w=55

        *(float4*)(ob + (size_t)c * CPLANE + l0) = make_float4(o0, o1, o2, o3);
    }
}
} // namespace

extern "C" void kernel_launch(void* const* d_in, const int* in_sizes, int n_in,
                              void* d_out, int out_size, void* d_ws, size_t ws_size,
                              hipStream_t stream) {
    const float* x  = (const float*)d_in[0];
    const float* w0 = (const float*)d_in[1];
    const float* w1 = (const float*)d_in[2];
    float* out = (float*)d_out;
    fused_kernel<<<dim3(128 * HH), dim3(128), 0, stream>>>(x, w0, w1, out);
}